// Round 10
// baseline (163.336 us; speedup 1.0000x reference)
//
#include <hip/hip_runtime.h>
#include <math.h>

#define NTOK 16384
#define DIM  4096
#define NEXP 64
#define KS   4                // K-split factor
#define KSL  (DIM / KS)       // 1024 k per slice
#define NCH  (KSL / 32)       // 32 chunks of 32 per slice
#define BM   64               // tokens per block (4 waves x 16)

typedef __fp16 f16x8 __attribute__((ext_vector_type(8)));
typedef __fp16 f16x2 __attribute__((ext_vector_type(2)));
typedef float  f32x4 __attribute__((ext_vector_type(4)));

__device__ __forceinline__ void gl_lds16(const void* g, void* l) {
  __builtin_amdgcn_global_load_lds(
      (const __attribute__((address_space(1))) void*)g,
      (__attribute__((address_space(3))) void*)l, 16, 0, 0);
}

// ---- prep: split W (fp32) into 2 fp16 planes (RNE hi, RNE residual) ----
__global__ __launch_bounds__(256) void split_w(
    const float* __restrict__ W,
    __fp16* __restrict__ Wh,
    __fp16* __restrict__ Wl)
{
  const int i = blockIdx.x * 256 + threadIdx.x;   // grid covers 64*4096
  const float w = W[i];
  const __fp16 h = (__fp16)w;                     // RNE
  const float r = w - (float)h;                   // exact
  Wh[i] = h;
  Wl[i] = (__fp16)r;                              // RNE, residual ~2^-24|w|
}

// ---- phase 1: BARRIER-FREE. A: gl_lds -> wave-private LDS triple buffer,
// ordered by counted per-wave vmcnt. B: direct per-lane loads from L2.
__global__ __launch_bounds__(256, 4) void router_mfma(
    const float* __restrict__ tokens,
    const __fp16* __restrict__ Wh,
    const __fp16* __restrict__ Wl,
    float* __restrict__ partial)   // [KS][NTOK][NEXP]
{
  __shared__ float As[4][3][16 * 32];   // [wave][buf][16 rows][32 f32] = 24 KB

  const int tid  = threadIdx.x;
  const int wid  = tid >> 6;
  const int lane = tid & 63;
  const int rc   = lane & 15;           // A-row / B-col within 16
  const int q    = lane >> 4;           // k-group (0..3)
  const int s    = blockIdx.x & (KS - 1);
  const int wrow = (blockIdx.x >> 2) * BM + 16 * wid;  // wave's 16 tokens
  const int kbase = s * KSL;

  // A staging source (pre-swizzled global, linear LDS dest): 2 instrs/chunk,
  // instr covers 8 rows x 128B; lane -> row (lane>>3), quad (lane&7)^(row&7)
  const int a_tl = lane >> 3, a_j = lane & 7;
  const float* asrc0 = tokens + (size_t)(wrow + a_tl) * DIM + kbase
                       + ((a_j ^ a_tl) << 2);
  const float* asrc1 = asrc0 + (size_t)8 * DIM;

  // B fragment pointers (L2-resident planes); chunk c lives at index 4c
  const f16x8* bp0 = (const f16x8*)(Wh + (size_t)( 0 + rc) * DIM + kbase + q * 8);
  const f16x8* bp1 = (const f16x8*)(Wh + (size_t)(16 + rc) * DIM + kbase + q * 8);
  const f16x8* bp2 = (const f16x8*)(Wh + (size_t)(32 + rc) * DIM + kbase + q * 8);
  const f16x8* bp3 = (const f16x8*)(Wh + (size_t)(48 + rc) * DIM + kbase + q * 8);
  const f16x8* lp0 = (const f16x8*)(Wl + (size_t)( 0 + rc) * DIM + kbase + q * 8);
  const f16x8* lp1 = (const f16x8*)(Wl + (size_t)(16 + rc) * DIM + kbase + q * 8);
  const f16x8* lp2 = (const f16x8*)(Wl + (size_t)(32 + rc) * DIM + kbase + q * 8);
  const f16x8* lp3 = (const f16x8*)(Wl + (size_t)(48 + rc) * DIM + kbase + q * 8);

  f32x4 acc0 = {0,0,0,0}, acc1 = {0,0,0,0}, acc2 = {0,0,0,0}, acc3 = {0,0,0,0};

  // read-side swizzled slots (constant per thread)
  const int sa0 = (2 * q) ^ (rc & 7), sa1 = (2 * q + 1) ^ (rc & 7);

#define STAGE(buf, c) {                               \
    const int ko = (c) * 32;                          \
    gl_lds16(asrc0 + ko, &As[wid][buf][0]);           \
    gl_lds16(asrc1 + ko, &As[wid][buf][8 * 32]);      \
  }

#define VM(n) asm volatile("s_waitcnt vmcnt(" #n ")" ::: "memory")

#define COMP(buf, c) {                                                       \
    const float4 a0 = *(const float4*)(&As[wid][buf][rc * 32 + sa0 * 4]);    \
    const float4 a1 = *(const float4*)(&As[wid][buf][rc * 32 + sa1 * 4]);    \
    const f16x8 bh0 = bp0[4 * (c)]; const f16x8 bh1 = bp1[4 * (c)];          \
    const f16x8 bh2 = bp2[4 * (c)]; const f16x8 bh3 = bp3[4 * (c)];          \
    const f16x8 bl0 = lp0[4 * (c)]; const f16x8 bl1 = lp1[4 * (c)];          \
    const f16x8 bl2 = lp2[4 * (c)]; const f16x8 bl3 = lp3[4 * (c)];          \
    const f16x2 h0 = __builtin_amdgcn_cvt_pkrtz(a0.x, a0.y);                 \
    const f16x2 h1 = __builtin_amdgcn_cvt_pkrtz(a0.z, a0.w);                 \
    const f16x2 h2 = __builtin_amdgcn_cvt_pkrtz(a1.x, a1.y);                 \
    const f16x2 h3 = __builtin_amdgcn_cvt_pkrtz(a1.z, a1.w);                 \
    const f16x2 m0 = __builtin_amdgcn_cvt_pkrtz(a0.x - (float)h0[0],         \
                                                a0.y - (float)h0[1]);        \
    const f16x2 m1 = __builtin_amdgcn_cvt_pkrtz(a0.z - (float)h1[0],         \
                                                a0.w - (float)h1[1]);        \
    const f16x2 m2 = __builtin_amdgcn_cvt_pkrtz(a1.x - (float)h2[0],         \
                                                a1.y - (float)h2[1]);        \
    const f16x2 m3 = __builtin_amdgcn_cvt_pkrtz(a1.z - (float)h3[0],         \
                                                a1.w - (float)h3[1]);        \
    const f16x8 Ah = {h0[0],h0[1],h1[0],h1[1],h2[0],h2[1],h3[0],h3[1]};      \
    const f16x8 Am = {m0[0],m0[1],m1[0],m1[1],m2[0],m2[1],m3[0],m3[1]};      \
    acc0 = __builtin_amdgcn_mfma_f32_16x16x32_f16(Ah, bh0, acc0, 0, 0, 0);   \
    acc1 = __builtin_amdgcn_mfma_f32_16x16x32_f16(Ah, bh1, acc1, 0, 0, 0);   \
    acc2 = __builtin_amdgcn_mfma_f32_16x16x32_f16(Ah, bh2, acc2, 0, 0, 0);   \
    acc3 = __builtin_amdgcn_mfma_f32_16x16x32_f16(Ah, bh3, acc3, 0, 0, 0);   \
    acc0 = __builtin_amdgcn_mfma_f32_16x16x32_f16(Am, bh0, acc0, 0, 0, 0);   \
    acc1 = __builtin_amdgcn_mfma_f32_16x16x32_f16(Am, bh1, acc1, 0, 0, 0);   \
    acc2 = __builtin_amdgcn_mfma_f32_16x16x32_f16(Am, bh2, acc2, 0, 0, 0);   \
    acc3 = __builtin_amdgcn_mfma_f32_16x16x32_f16(Am, bh3, acc3, 0, 0, 0);   \
    acc0 = __builtin_amdgcn_mfma_f32_16x16x32_f16(Ah, bl0, acc0, 0, 0, 0);   \
    acc1 = __builtin_amdgcn_mfma_f32_16x16x32_f16(Ah, bl1, acc1, 0, 0, 0);   \
    acc2 = __builtin_amdgcn_mfma_f32_16x16x32_f16(Ah, bl2, acc2, 0, 0, 0);   \
    acc3 = __builtin_amdgcn_mfma_f32_16x16x32_f16(Ah, bl3, acc3, 0, 0, 0);   \
  }

  // prologue: 2 chunks in flight, then steady-state 2-ahead, no barriers.
  // vmcnt(12) derivation: newer-than-A(c) at the wait = A(c+2)[2] + B(c+1)[8]
  // + A(c+1)[2] = 12; in-order retirement (m135) => A(c) landed.
  STAGE(0, 0); STAGE(1, 1);
  STAGE(2, 2); VM(4);  COMP(0, 0);
  for (int i = 0; i < 9; ++i) {
    const int c = 1 + 3 * i;            // c = 1,4,...,25
    STAGE(0, c + 2); VM(12); COMP(1, c);
    STAGE(1, c + 3); VM(12); COMP(2, c + 1);
    STAGE(2, c + 4); VM(12); COMP(0, c + 2);
  }
  STAGE(0, 30); VM(12); COMP(1, 28);
  STAGE(1, 31); VM(12); COMP(2, 29);
  VM(2);  COMP(0, 30);
  VM(0);  COMP(1, 31);
#undef STAGE
#undef COMP
#undef VM

  // write partial logits: D row = q*4+rr (token within 16), col = 16t+rc
  float* P = partial + ((size_t)s * NTOK + wrow) * NEXP;
  #pragma unroll
  for (int rr = 0; rr < 4; ++rr) {
    const int row = q * 4 + rr;
    P[(size_t)row * NEXP +  0 + rc] = acc0[rr];
    P[(size_t)row * NEXP + 16 + rc] = acc1[rr];
    P[(size_t)row * NEXP + 32 + rc] = acc2[rr];
    P[(size_t)row * NEXP + 48 + rc] = acc3[rr];
  }
}

// ---- phase 2: reduce partials, softmax + top-2 ----
__global__ __launch_bounds__(64) void router_finish(
    const float* __restrict__ partial,
    float* __restrict__ out)
{
  const int t = blockIdx.x * 64 + threadIdx.x;

  float l[NEXP];
  const float* p0 = partial + (size_t)t * NEXP;
  #pragma unroll
  for (int qq = 0; qq < 16; ++qq) {
    const float4 v = *(const float4*)(p0 + qq * 4);
    l[qq*4+0] = v.x; l[qq*4+1] = v.y; l[qq*4+2] = v.z; l[qq*4+3] = v.w;
  }
  #pragma unroll
  for (int s = 1; s < KS; ++s) {
    const float* p = partial + ((size_t)s * NTOK + t) * NEXP;
    #pragma unroll
    for (int qq = 0; qq < 16; ++qq) {
      const float4 v = *(const float4*)(p + qq * 4);
      l[qq*4+0] += v.x; l[qq*4+1] += v.y; l[qq*4+2] += v.z; l[qq*4+3] += v.w;
    }
  }

  // top-2, lax.top_k tie-break (ascending scan with strict > keeps lower idx)
  float t1v = l[0]; int t1i = 0;
  float t2v = -INFINITY; int t2i = NEXP;
  #pragma unroll
  for (int e = 1; e < NEXP; ++e) {
    const float v = l[e];
    if (v > t1v) { t2v = t1v; t2i = t1i; t1v = v; t1i = e; }
    else if (v > t2v) { t2v = v; t2i = e; }
  }

  float ssum = 0.f;
  #pragma unroll
  for (int e = 0; e < NEXP; ++e) ssum += expf(l[e] - t1v);

  const float inv = 1.0f / ssum;
  out[t * 2 + 0] = inv;
  out[t * 2 + 1] = expf(t2v - t1v) * inv;
  out[2 * NTOK + t * 2 + 0] = (float)t1i;
  out[2 * NTOK + t * 2 + 1] = (float)t2i;
}

extern "C" void kernel_launch(void* const* d_in, const int* in_sizes, int n_in,
                              void* d_out, int out_size, void* d_ws, size_t ws_size,
                              hipStream_t stream) {
  const float* tokens = (const float*)d_in[0];
  const float* W      = (const float*)d_in[1];
  float* out          = (float*)d_out;

  __fp16* Wh = (__fp16*)d_ws;
  __fp16* Wl = Wh + (size_t)NEXP * DIM;
  float* partial = (float*)((char*)d_ws + (size_t)2 * NEXP * DIM * sizeof(__fp16));

  split_w<<<(NEXP * DIM) / 256, 256, 0, stream>>>(W, Wh, Wl);
  router_mfma<<<(NTOK / BM) * KS, 256, 0, stream>>>(tokens, Wh, Wl, partial);
  router_finish<<<NTOK / 64, 64, 0, stream>>>(partial, out);
}

// Round 11
// 72.558 us; speedup vs baseline: 2.2511x; 2.2511x over previous
//
#include <hip/hip_runtime.h>
#include <math.h>

#define NTOK 16384
#define DIM  4096
#define NEXP 64
#define KS   2                // K-split factor
#define KSL  (DIM / KS)       // 2048 k per slice
#define BK   64               // k per chunk
#define NCH  (KSL / BK)       // 32 chunks
#define BM   64               // tokens per block (2x2 waves of 32x32)

typedef __fp16 f16x8  __attribute__((ext_vector_type(8)));
typedef __fp16 f16x2  __attribute__((ext_vector_type(2)));
typedef float  f32x16 __attribute__((ext_vector_type(16)));

__device__ __forceinline__ void gl_lds16(const void* g, void* l) {
  __builtin_amdgcn_global_load_lds(
      (const __attribute__((address_space(1))) void*)g,
      (__attribute__((address_space(3))) void*)l, 16, 0, 0);
}

// ---- prep: split W (fp32) into 2 fp16 planes (RNE hi, RNE residual) ----
__global__ __launch_bounds__(256) void split_w(
    const float* __restrict__ W,
    __fp16* __restrict__ Wh,
    __fp16* __restrict__ Wl)
{
  const int i = blockIdx.x * 256 + threadIdx.x;   // grid covers 64*4096
  const float w = W[i];
  const __fp16 h = (__fp16)w;                     // RNE
  const float r = w - (float)h;                   // exact
  Wh[i] = h;
  Wl[i] = (__fp16)r;                              // RNE, residual ~2^-24|w|
}

// ---- phase 1: 32x32x16 MFMA, gl_lds double-buffer, r7 sync structure ----
__global__ __launch_bounds__(256, 2) void router_mfma(
    const float* __restrict__ tokens,
    const __fp16* __restrict__ Wh,
    const __fp16* __restrict__ Wl,
    float* __restrict__ partial)   // [KS][NTOK][NEXP]
{
  __shared__ float  As[2][BM * BK];     // 2 x 16 KB
  __shared__ __fp16 Bh[2][NEXP * BK];   // 2 x 8 KB
  __shared__ __fp16 Bl[2][NEXP * BK];   // 2 x 8 KB   -> 64 KB

  const int tid  = threadIdx.x;
  const int wid  = tid >> 6;
  const int lane = tid & 63;
  const int rc2  = lane & 31;           // MFMA row/col within 32
  const int q2   = lane >> 5;           // k-half
  const int wr   = wid >> 1;            // token 32-half
  const int ec   = wid & 1;             // expert 32-half
  const int s    = blockIdx.x & (KS - 1);
  const int tb   = (blockIdx.x >> 1) * BM;   // block token base
  const int kbase = s * KSL;

  // ---- staging sources (pre-swizzled global, linear LDS dest: G21) ----
  // A: wave stages rows 16*wid+4i+(lane>>4); row=64 f32=16 units; key=r&15
  const int l16 = lane >> 4;            // 0..3
  const int aj  = lane & 15;            // 16B unit within row
  const float* ap0 = tokens + (size_t)(tb + 16*wid +  0 + l16) * DIM + kbase + ((aj ^ ( 0 + l16)) << 2);
  const float* ap1 = tokens + (size_t)(tb + 16*wid +  4 + l16) * DIM + kbase + ((aj ^ ( 4 + l16)) << 2);
  const float* ap2 = tokens + (size_t)(tb + 16*wid +  8 + l16) * DIM + kbase + ((aj ^ ( 8 + l16)) << 2);
  const float* ap3 = tokens + (size_t)(tb + 16*wid + 12 + l16) * DIM + kbase + ((aj ^ (12 + l16)) << 2);
  // B: wave stages experts 16*wid+8i+(lane>>3); row=64 f16=8 units; key=e&7
  const int l8 = lane >> 3;             // 0..7
  const int bj = lane & 7;              // 16B unit within row
  const size_t bo0 = (size_t)(16*wid + 0 + l8) * DIM + kbase + ((bj ^ l8) << 3);
  const size_t bo1 = (size_t)(16*wid + 8 + l8) * DIM + kbase + ((bj ^ l8) << 3);
  const __fp16* bh0s = Wh + bo0; const __fp16* bh1s = Wh + bo1;
  const __fp16* bl0s = Wl + bo0; const __fp16* bl1s = Wl + bo1;

#define STAGE(buf, c) {                                          \
    const int ko = (c) * BK;                                     \
    gl_lds16(ap0 + ko, &As[buf][(16 * wid +  0) * BK]);          \
    gl_lds16(ap1 + ko, &As[buf][(16 * wid +  4) * BK]);          \
    gl_lds16(ap2 + ko, &As[buf][(16 * wid +  8) * BK]);          \
    gl_lds16(ap3 + ko, &As[buf][(16 * wid + 12) * BK]);          \
    gl_lds16(bh0s + ko, &Bh[buf][(16 * wid + 0) * BK]);          \
    gl_lds16(bh1s + ko, &Bh[buf][(16 * wid + 8) * BK]);          \
    gl_lds16(bl0s + ko, &Bl[buf][(16 * wid + 0) * BK]);          \
    gl_lds16(bl1s + ko, &Bl[buf][(16 * wid + 8) * BK]);          \
  }

  f32x16 acc = {0,0,0,0, 0,0,0,0, 0,0,0,0, 0,0,0,0};

  // read-side constants
  const int akey = rc2 & 15;
  const int bkey = rc2 & 7;
  const int Arow = (32 * wr + rc2) * BK;
  const int Brow = (32 * ec + rc2) * BK;

#define KSTEP(buf, kk) {                                                     \
    const int u0 = 4 * (kk) + 2 * q2;                                        \
    const float4 a0 = *(const float4*)(&As[buf][Arow + ((u0    ) ^ akey) * 4]); \
    const float4 a1 = *(const float4*)(&As[buf][Arow + ((u0 + 1) ^ akey) * 4]); \
    const int ub = ((2 * (kk) + q2) ^ bkey) * 8;                             \
    const f16x8 bhv = *(const f16x8*)(&Bh[buf][Brow + ub]);                  \
    const f16x8 blv = *(const f16x8*)(&Bl[buf][Brow + ub]);                  \
    const f16x2 h0 = __builtin_amdgcn_cvt_pkrtz(a0.x, a0.y);                 \
    const f16x2 h1 = __builtin_amdgcn_cvt_pkrtz(a0.z, a0.w);                 \
    const f16x2 h2 = __builtin_amdgcn_cvt_pkrtz(a1.x, a1.y);                 \
    const f16x2 h3 = __builtin_amdgcn_cvt_pkrtz(a1.z, a1.w);                 \
    const f16x2 m0 = __builtin_amdgcn_cvt_pkrtz(a0.x - (float)h0[0],         \
                                                a0.y - (float)h0[1]);        \
    const f16x2 m1 = __builtin_amdgcn_cvt_pkrtz(a0.z - (float)h1[0],         \
                                                a0.w - (float)h1[1]);        \
    const f16x2 m2 = __builtin_amdgcn_cvt_pkrtz(a1.x - (float)h2[0],         \
                                                a1.y - (float)h2[1]);        \
    const f16x2 m3 = __builtin_amdgcn_cvt_pkrtz(a1.z - (float)h3[0],         \
                                                a1.w - (float)h3[1]);        \
    const f16x8 Ah = {h0[0],h0[1],h1[0],h1[1],h2[0],h2[1],h3[0],h3[1]};      \
    const f16x8 Am = {m0[0],m0[1],m1[0],m1[1],m2[0],m2[1],m3[0],m3[1]};      \
    acc = __builtin_amdgcn_mfma_f32_32x32x16_f16(Ah, bhv, acc, 0, 0, 0);     \
    acc = __builtin_amdgcn_mfma_f32_32x32x16_f16(Ah, blv, acc, 0, 0, 0);     \
    acc = __builtin_amdgcn_mfma_f32_32x32x16_f16(Am, bhv, acc, 0, 0, 0);     \
  }

#define COMP(buf) { KSTEP(buf, 0); KSTEP(buf, 1); KSTEP(buf, 2); KSTEP(buf, 3); }

  // prologue
  STAGE(0, 0);
  __syncthreads();

  // main loop: r7-proven 1-barrier-per-chunk double buffer
  for (int c = 0; c < NCH; c += 2) {
    if (c + 1 < NCH) STAGE(1, c + 1);
    COMP(0);
    __syncthreads();
    if (c + 2 < NCH) STAGE(0, c + 2);
    COMP(1);
    __syncthreads();
  }
#undef STAGE
#undef COMP
#undef KSTEP

  // write partial logits: D col = rc2 (expert within 32),
  // D row = (reg&3) + 8*(reg>>2) + 4*q2 (token within 32)  [m74-verified]
  float* P = partial + ((size_t)s * NTOK + tb + 32 * wr) * NEXP + 32 * ec;
  #pragma unroll
  for (int reg = 0; reg < 16; ++reg) {
    const int row = (reg & 3) + 8 * (reg >> 2) + 4 * q2;
    P[(size_t)row * NEXP + rc2] = acc[reg];
  }
}

// ---- phase 2: reduce partials, softmax + top-2 ----
__global__ __launch_bounds__(64) void router_finish(
    const float* __restrict__ partial,
    float* __restrict__ out)
{
  const int t = blockIdx.x * 64 + threadIdx.x;

  float l[NEXP];
  const float* p0 = partial + (size_t)t * NEXP;
  #pragma unroll
  for (int qq = 0; qq < 16; ++qq) {
    const float4 v = *(const float4*)(p0 + qq * 4);
    l[qq*4+0] = v.x; l[qq*4+1] = v.y; l[qq*4+2] = v.z; l[qq*4+3] = v.w;
  }
  #pragma unroll
  for (int s = 1; s < KS; ++s) {
    const float* p = partial + ((size_t)s * NTOK + t) * NEXP;
    #pragma unroll
    for (int qq = 0; qq < 16; ++qq) {
      const float4 v = *(const float4*)(p + qq * 4);
      l[qq*4+0] += v.x; l[qq*4+1] += v.y; l[qq*4+2] += v.z; l[qq*4+3] += v.w;
    }
  }

  // top-2, lax.top_k tie-break (ascending scan with strict > keeps lower idx)
  float t1v = l[0]; int t1i = 0;
  float t2v = -INFINITY; int t2i = NEXP;
  #pragma unroll
  for (int e = 1; e < NEXP; ++e) {
    const float v = l[e];
    if (v > t1v) { t2v = t1v; t2i = t1i; t1v = v; t1i = e; }
    else if (v > t2v) { t2v = v; t2i = e; }
  }

  float ssum = 0.f;
  #pragma unroll
  for (int e = 0; e < NEXP; ++e) ssum += expf(l[e] - t1v);

  const float inv = 1.0f / ssum;
  out[t * 2 + 0] = inv;
  out[t * 2 + 1] = expf(t2v - t1v) * inv;
  out[2 * NTOK + t * 2 + 0] = (float)t1i;
  out[2 * NTOK + t * 2 + 1] = (float)t2i;
}

extern "C" void kernel_launch(void* const* d_in, const int* in_sizes, int n_in,
                              void* d_out, int out_size, void* d_ws, size_t ws_size,
                              hipStream_t stream) {
  const float* tokens = (const float*)d_in[0];
  const float* W      = (const float*)d_in[1];
  float* out          = (float*)d_out;

  __fp16* Wh = (__fp16*)d_ws;
  __fp16* Wl = Wh + (size_t)NEXP * DIM;
  float* partial = (float*)((char*)d_ws + (size_t)2 * NEXP * DIM * sizeof(__fp16));

  split_w<<<(NEXP * DIM) / 256, 256, 0, stream>>>(W, Wh, Wl);
  router_mfma<<<(NTOK / BM) * KS, 256, 0, stream>>>(tokens, Wh, Wl, partial);
  router_finish<<<NTOK / 64, 64, 0, stream>>>(partial, out);
}